// Round 3
// baseline (694.883 us; speedup 1.0000x reference)
//
#include <hip/hip_runtime.h>
#include <math.h>

#define ROWS 65536
#define DIM  256
#define KC   1024
#define NQ   (ROWS * DIM)

// ---- ws layout (bytes) ----
// [0]      double lossacc
// [16]     int    counts[1024]          (ends 4112)
// [4224]   float  B32[1024]             (ends 8320)
// [8320]   float  Arr[65536]            (ends 270464)
// [270464] u64    packed[65536]         (ends 794752)   (distbits<<32)|idx

// ---------------------------------------------------------------------------
// numpy pairwise sum-of-squares for 256 contiguous fp32 (replicates
// numpy's scalar pairwise_sum: two 128-halves, 8 accumulators each,
// tree ((r0+r1)+(r2+r3))+((r4+r5)+(r6+r7)), halves added at the end).
// ---------------------------------------------------------------------------
__device__ __forceinline__ float sq_sum_numpy(const float* __restrict__ p) {
    float halves[2];
#pragma unroll
    for (int h = 0; h < 2; ++h) {
        const float* a = p + h * 128;
        float4 u0 = *(const float4*)(a);
        float4 u1 = *(const float4*)(a + 4);
        float r0 = __fmul_rn(u0.x, u0.x);
        float r1 = __fmul_rn(u0.y, u0.y);
        float r2 = __fmul_rn(u0.z, u0.z);
        float r3 = __fmul_rn(u0.w, u0.w);
        float r4 = __fmul_rn(u1.x, u1.x);
        float r5 = __fmul_rn(u1.y, u1.y);
        float r6 = __fmul_rn(u1.z, u1.z);
        float r7 = __fmul_rn(u1.w, u1.w);
        for (int i = 8; i < 128; i += 8) {
            float4 v0 = *(const float4*)(a + i);
            float4 v1 = *(const float4*)(a + i + 4);
            r0 = __fadd_rn(r0, __fmul_rn(v0.x, v0.x));
            r1 = __fadd_rn(r1, __fmul_rn(v0.y, v0.y));
            r2 = __fadd_rn(r2, __fmul_rn(v0.z, v0.z));
            r3 = __fadd_rn(r3, __fmul_rn(v0.w, v0.w));
            r4 = __fadd_rn(r4, __fmul_rn(v1.x, v1.x));
            r5 = __fadd_rn(r5, __fmul_rn(v1.y, v1.y));
            r6 = __fadd_rn(r6, __fmul_rn(v1.z, v1.z));
            r7 = __fadd_rn(r7, __fmul_rn(v1.w, v1.w));
        }
        float s01 = __fadd_rn(r0, r1);
        float s23 = __fadd_rn(r2, r3);
        float s45 = __fadd_rn(r4, r5);
        float s67 = __fadd_rn(r6, r7);
        halves[h] = __fadd_rn(__fadd_rn(s01, s23), __fadd_rn(s45, s67));
    }
    return __fadd_rn(halves[0], halves[1]);
}

__global__ __launch_bounds__(256) void k_prepB(const float* __restrict__ E,
                                               float* __restrict__ B32) {
    int j = blockIdx.x * 256 + threadIdx.x;
    if (j >= KC) return;
    B32[j] = sq_sum_numpy(E + (size_t)j * DIM);
}

__global__ __launch_bounds__(256) void k_prepA(const float* __restrict__ X,
                                               float* __restrict__ Arr) {
    int r = blockIdx.x * 256 + threadIdx.x;
    Arr[r] = sq_sum_numpy(X + (size_t)r * DIM);
}

// ---------------- K1: fp32 dist + first-index argmin -----------------------
// Split-K: blockIdx.y in {0,1} handles cols [y*512, y*512+512).
// Tiles: 128 rows x 128 cols per cb iter, D in chunks of 32.
// LDS: row-major [r][d] / [c][d], stride 36 floats (144B): b128 staging
// writes are conflict-free (start banks tile all 32); fragment reads along d
// hit 2-way max aliasing (free). Interleaved ownership: thread (tx,ty) owns
// rows ty+16i, cols tx+16j. Each acc[i][j] is ONE ascending-d fmaf chain
// from 0 over d=0..255 -> bit-identical to OpenBLAS sgemm accumulation.
#define TM 128
#define TN 128
#define TD 32
#define STR 36          // floats; 144 B row stride, 16B-aligned

__global__ __launch_bounds__(256, 4) void k_pass1(
    const float* __restrict__ X, const float* __restrict__ E,
    const float* __restrict__ B32, const float* __restrict__ Arr,
    unsigned long long* __restrict__ packed)
{
    __shared__ float sm[2 * TM * STR];   // 36864 B
    float* Xs = sm;                      // [128][36]
    float* Es = sm + TM * STR;           // [128][36]

    const int tid = threadIdx.x;
    const int tx = tid & 15;
    const int ty = tid >> 4;
    const int rowbase = blockIdx.x * TM;
    const int colbase = blockIdx.y * 512;

    float a8[8];
#pragma unroll
    for (int i = 0; i < 8; ++i) a8[i] = Arr[rowbase + ty + 16 * i];

    float v1[8]; int i1[8];
#pragma unroll
    for (int i = 0; i < 8; ++i) { v1[i] = 3.0e38f; i1[i] = 0; }

    for (int cb = 0; cb < 512; cb += TN) {
        float acc[8][8];
#pragma unroll
        for (int i = 0; i < 8; ++i)
#pragma unroll
            for (int j = 0; j < 8; ++j) acc[i][j] = 0.0f;

        for (int dc = 0; dc < DIM; dc += TD) {
            __syncthreads();
            // stage 128x32 of X and E, row-major stride-36, b128 writes
#pragma unroll
            for (int k = 0; k < 4; ++k) {
                int fi = tid + k * 256;            // 0..1023
                int r  = fi >> 3;                  // 0..127
                int g4 = (fi & 7) * 4;             // 0,4,...,28
                float4 xv = *(const float4*)(X + (size_t)(rowbase + r) * DIM + dc + g4);
                *(float4*)&Xs[r * STR + g4] = xv;
                float4 ev = *(const float4*)(E + (size_t)(colbase + cb + r) * DIM + dc + g4);
                *(float4*)&Es[r * STR + g4] = ev;
            }
            __syncthreads();

            // compute: 8 groups of 4 d's; fragments read as float4 along d
#pragma unroll
            for (int gg = 0; gg < 8; ++gg) {
                float4 e4[8];
#pragma unroll
                for (int j = 0; j < 8; ++j)
                    e4[j] = *(float4*)&Es[(tx + 16 * j) * STR + gg * 4];
#pragma unroll
                for (int i = 0; i < 8; ++i) {
                    float4 x4 = *(float4*)&Xs[(ty + 16 * i) * STR + gg * 4];
#pragma unroll
                    for (int j = 0; j < 8; ++j) {
                        acc[i][j] = fmaf(x4.x, e4[j].x, acc[i][j]);
                        acc[i][j] = fmaf(x4.y, e4[j].y, acc[i][j]);
                        acc[i][j] = fmaf(x4.z, e4[j].z, acc[i][j]);
                        acc[i][j] = fmaf(x4.w, e4[j].w, acc[i][j]);
                    }
                }
            }
        }

        // fold: dist = fl(fl(A + B) - fl(2*dot)), numpy rounding; strict <
        // keeps lowest c per thread (c ascends with j and cb).
#pragma unroll
        for (int j = 0; j < 8; ++j) {
            int c = colbase + cb + tx + 16 * j;
            float b = B32[c];
#pragma unroll
            for (int i = 0; i < 8; ++i) {
                float Cv  = __fmul_rn(2.0f, acc[i][j]);
                float t1v = __fadd_rn(a8[i], b);
                float dv  = __fsub_rn(t1v, Cv);
                if (dv < v1[i]) { v1[i] = dv; i1[i] = c; }
            }
        }
    }

    // merge (val, idx) across the 16 col-threads per row via LDS
    __syncthreads();
    float* Mv = sm;                        // [128][16] floats
    int*   Mi = (int*)(sm + 2048);         // [128][16] ints
#pragma unroll
    for (int i = 0; i < 8; ++i) {
        int r = ty + 16 * i;
        Mv[r * 16 + tx] = v1[i];
        Mi[r * 16 + tx] = i1[i];
    }
    __syncthreads();
    if (tid < TM) {
        int r = tid;
        float bv = Mv[r * 16];
        int   bi = Mi[r * 16];
        for (int t = 1; t < 16; ++t) {
            float av = Mv[r * 16 + t];
            int   ai = Mi[r * 16 + t];
            if (av < bv || (av == bv && ai < bi)) { bv = av; bi = ai; }
        }
        // dist > 0 always here (A ~ 256 dominates) -> IEEE bits are
        // order-preserving; ties resolve to lower idx. Global first-index.
        unsigned long long pk =
            ((unsigned long long)__float_as_uint(bv) << 32) |
            (unsigned long long)(unsigned)bi;
        atomicMin(&packed[rowbase + r], pk);
    }
}

// ---------------- K3: gather quantized + fp64 loss accumulation ------------
__global__ __launch_bounds__(256) void k_out(
    const float* __restrict__ X, const float* __restrict__ E,
    const unsigned long long* __restrict__ packed, float* __restrict__ out0,
    double* __restrict__ lossacc)
{
    const int NF4 = NQ / 4;
    double s = 0.0;
    for (int g = blockIdx.x * blockDim.x + threadIdx.x; g < NF4;
         g += gridDim.x * blockDim.x) {
        int row = g >> 6;
        int d4  = g & 63;
        int j = (int)(packed[row] & 0xffffffffULL);
        float4 q = *(const float4*)(E + (size_t)j * DIM + d4 * 4);
        float4 x = *(const float4*)(X + (size_t)g * 4);
        *(float4*)(out0 + (size_t)g * 4) = q;
        double dx;
        dx = (double)q.x - (double)x.x; s = fma(dx, dx, s);
        dx = (double)q.y - (double)x.y; s = fma(dx, dx, s);
        dx = (double)q.z - (double)x.z; s = fma(dx, dx, s);
        dx = (double)q.w - (double)x.w; s = fma(dx, dx, s);
    }
#pragma unroll
    for (int off = 32; off > 0; off >>= 1) s += __shfl_down(s, off, 64);
    __shared__ double wsum[4];
    int lane = threadIdx.x & 63, wv = threadIdx.x >> 6;
    if (lane == 0) wsum[wv] = s;
    __syncthreads();
    if (threadIdx.x == 0) {
        double t = wsum[0] + wsum[1] + wsum[2] + wsum[3];
        atomicAdd(lossacc, t);
    }
}

// ---------------- K3b: index output + histogram ----------------------------
__global__ __launch_bounds__(256) void k_idxout(
    const unsigned long long* __restrict__ packed, float* __restrict__ out1,
    int* __restrict__ counts)
{
    __shared__ int h[KC];
    for (int i = threadIdx.x; i < KC; i += 256) h[i] = 0;
    __syncthreads();
    int r = blockIdx.x * 256 + threadIdx.x;   // grid 256*256 = 65536 exact
    int j = (int)(packed[r] & 0xffffffffULL);
    out1[r] = (float)j;
    atomicAdd(&h[j], 1);
    __syncthreads();
    for (int i = threadIdx.x; i < KC; i += 256)
        if (h[i]) atomicAdd(&counts[i], h[i]);
}

// ---------------- K4: perplexity + loss finalize ---------------------------
__global__ void k_fin(const int* __restrict__ counts,
                      const double* __restrict__ lossacc,
                      float* __restrict__ out_pl)
{
    __shared__ double sh[256];
    double s = 0.0;
    for (int i = threadIdx.x; i < KC; i += 256) {
        double p = (double)counts[i] / 65536.0;
        s += p * log(p + 1.1920928955078125e-07);   // EPS = fp32 eps exactly
    }
    sh[threadIdx.x] = s;
    __syncthreads();
    for (int off = 128; off > 0; off >>= 1) {
        if (threadIdx.x < off) sh[threadIdx.x] += sh[threadIdx.x + off];
        __syncthreads();
    }
    if (threadIdx.x == 0) {
        out_pl[0] = (float)exp(-sh[0]);
        out_pl[1] = (float)((*lossacc / (double)NQ) * 1.1);  // q + 0.1*e
    }
}

extern "C" void kernel_launch(void* const* d_in, const int* in_sizes, int n_in,
                              void* d_out, int out_size, void* d_ws, size_t ws_size,
                              hipStream_t stream) {
    const float* X = (const float*)d_in[0];
    const float* E = (const float*)d_in[1];
    float* out = (float*)d_out;
    char* ws = (char*)d_ws;

    double* lossacc = (double*)(ws + 0);
    int*    counts  = (int*)(ws + 16);
    float*  B32     = (float*)(ws + 4224);
    float*  Arr     = (float*)(ws + 8320);
    unsigned long long* packed = (unsigned long long*)(ws + 270464);

    hipMemsetAsync(ws, 0, 4224, stream);               // lossacc + counts
    hipMemsetAsync(ws + 270464, 0xFF, 524288, stream); // packed = u64 max

    hipLaunchKernelGGL(k_prepB, dim3(4),   dim3(256), 0, stream, E, B32);
    hipLaunchKernelGGL(k_prepA, dim3(256), dim3(256), 0, stream, X, Arr);
    hipLaunchKernelGGL(k_pass1, dim3(ROWS / TM, 2), dim3(256), 0, stream,
                       X, E, B32, Arr, packed);
    hipLaunchKernelGGL(k_out,   dim3(2048), dim3(256), 0, stream,
                       X, E, packed, out, lossacc);
    hipLaunchKernelGGL(k_idxout, dim3(256), dim3(256), 0, stream,
                       packed, out + NQ, counts);
    hipLaunchKernelGGL(k_fin,   dim3(1),   dim3(256), 0, stream,
                       counts, lossacc, out + NQ + 65536);
}